// Round 6
// baseline (395.553 us; speedup 1.0000x reference)
//
#include <hip/hip_runtime.h>
#include <hip/hip_bf16.h>

typedef __hip_bfloat16 bf16;
__device__ __forceinline__ float bf2f(bf16 v) { return __bfloat162float(v); }

#define NPART 8        // XCD count; blockIdx % 8 ~ round-robin XCD heuristic
#define CHUNK 8192     // incidences per chunk in fill

// ===========================================================================
// Histogram, UNpartitioned (atomics are memory-side anyway; single 16MB read).
// ===========================================================================
__global__ __launch_bounds__(256) void hist_kernel(
    const int* __restrict__ vertex, const int* __restrict__ edges,
    int* __restrict__ counts, int nnz, int E) {
  const int stride = gridDim.x * 256;
  for (int i = blockIdx.x * 256 + threadIdx.x; i < nnz; i += stride) {
    const int e = __builtin_nontemporal_load(&edges[i]);
    const int v = __builtin_nontemporal_load(&vertex[i]);
    atomicAdd(&counts[e], 1);
    atomicAdd(&counts[E + v], 1);
  }
}

// 2048 elements per block: thread-local 8 + Hillis-Steele over 256 threads.
__global__ __launch_bounds__(256) void scan_blocks_kernel(
    const int* __restrict__ counts, int* __restrict__ offs,
    int* __restrict__ bsums, int M) {
  __shared__ int lds[256];
  const int tid  = threadIdx.x;
  const int base = blockIdx.x * 2048 + tid * 8;
  int v[8]; int tsum = 0;
#pragma unroll
  for (int j = 0; j < 8; ++j) {
    v[j] = (base + j < M) ? counts[base + j] : 0;
    tsum += v[j];
  }
  lds[tid] = tsum;
  __syncthreads();
  for (int off = 1; off < 256; off <<= 1) {
    int t = (tid >= off) ? lds[tid - off] : 0;
    __syncthreads();
    lds[tid] += t;
    __syncthreads();
  }
  int run = lds[tid] - tsum;
#pragma unroll
  for (int j = 0; j < 8; ++j) {
    if (base + j < M) offs[base + j] = run;
    run += v[j];
  }
  if (tid == 255) bsums[blockIdx.x] = lds[255];
}

__global__ void scan_sums_kernel(int* __restrict__ bsums, int* __restrict__ offs,
                                 int NB, int M) {
  if (threadIdx.x == 0 && blockIdx.x == 0) {
    int run = 0;
    for (int b = 0; b < NB; ++b) { int t = bsums[b]; bsums[b] = run; run += t; }
    offs[M] = run;   // == 2*nnz
  }
}

__global__ __launch_bounds__(256) void scan_add_kernel(
    int* __restrict__ offs, int* __restrict__ pos,
    const int* __restrict__ bsums, int M) {
  const int base = blockIdx.x * 2048 + threadIdx.x * 8;
  const int add = bsums[blockIdx.x];
#pragma unroll
  for (int j = 0; j < 8; ++j) {
    if (base + j < M) {
      const int t = offs[base + j] + add;
      offs[base + j] = t;
      pos[base + j] = t;
    }
  }
}

// ===========================================================================
// CSR fill, destination-partitioned + NT index loads: the perm write-window
// (~1MB/XCD) stays L2-resident because the streaming index reads no longer
// evict it -> 16 x 4B writes merge into one full-line writeback.
// ===========================================================================
__global__ __launch_bounds__(256) void fill_kernel(
    const int* __restrict__ vertex, const int* __restrict__ edges,
    int* __restrict__ pos, int* __restrict__ perm, int nnz, int E, int N) {
  const int part  = blockIdx.x % NPART;
  const int chunk = blockIdx.x / NPART;
  const int eLo = (int)((long long)E * part / NPART);
  const int eHi = (int)((long long)E * (part + 1) / NPART);
  const int vLo = (int)((long long)N * part / NPART);
  const int vHi = (int)((long long)N * (part + 1) / NPART);
  const int iEnd = min(nnz, (chunk + 1) * CHUNK);
  for (int i = chunk * CHUNK + threadIdx.x; i < iEnd; i += 256) {
    const int e = __builtin_nontemporal_load(&edges[i]);
    const int v = __builtin_nontemporal_load(&vertex[i]);
    if (e >= eLo && e < eHi) {
      const int p1 = atomicAdd(&pos[e], 1);
      perm[p1] = v;                     // edge-grouped: store vertex id
    }
    if (v >= vLo && v < vHi) {
      const int p2 = atomicAdd(&pos[E + v], 1);
      perm[p2] = e;                     // vertex-grouped: store edge id
    }
  }
}

// ===========================================================================
// GEMM: Xl[N,64] (bf16) = X[N,128] (f32) @ W[128,64] (f32). 32 rows/block.
// ===========================================================================
__global__ __launch_bounds__(256) void gemm_kernel(
    const float* __restrict__ X, const float* __restrict__ W,
    bf16* __restrict__ Xl, int Nrows) {
  __shared__ float ldsW[128 * 64];   // 32 KB
  __shared__ float ldsX[32][128];    // 16 KB

  const int tid = threadIdx.x;
  for (int i = tid; i < 128 * 64; i += 256) ldsW[i] = W[i];

  const int row0 = blockIdx.x * 32;
  {
    const int r    = tid >> 3;           // 0..31
    const int col0 = (tid & 7) * 16;     // 0..112
    const int rr   = row0 + r;
    if (rr < Nrows) {
      const float* src = X + (size_t)rr * 128 + col0;
      float* dst = &ldsX[r][col0];
#pragma unroll
      for (int q = 0; q < 4; ++q)
        *(float4*)(dst + q * 4) = *(const float4*)(src + q * 4);
    }
  }
  __syncthreads();

  const int c  = tid & 63;
  const int r0 = tid >> 6;       // 0..3; rows r0 + 4*j
  float acc[8];
#pragma unroll
  for (int j = 0; j < 8; ++j) acc[j] = 0.f;

  const float* __restrict__ wc = ldsW + c;
#pragma unroll 4
  for (int k = 0; k < 128; ++k) {
    const float w = wc[k * 64];
#pragma unroll
    for (int j = 0; j < 8; ++j)
      acc[j] += ldsX[r0 + j * 4][k] * w;
  }

#pragma unroll
  for (int j = 0; j < 8; ++j) {
    const int rr = row0 + r0 + j * 4;
    if (rr < Nrows) Xl[(size_t)rr * 64 + c] = __float2bfloat16(acc[j]);
  }
}

// ===========================================================================
// Gather 1: one wave per hyperedge. Xe[e] = degE[e]*W_edge[e] * sum_v Xl[v]
// ===========================================================================
__global__ __launch_bounds__(256) void gather_e_kernel(
    const bf16* __restrict__ Xl, const int* __restrict__ perm,
    const int* __restrict__ offs, const float* __restrict__ degE,
    const float* __restrict__ W_edge, bf16* __restrict__ Xe, int E) {
  const int gtid = blockIdx.x * 256 + threadIdx.x;
  const int e    = gtid >> 6;
  const int lane = gtid & 63;
  if (e >= E) return;

  const int beg = offs[e];
  const int end = offs[e + 1];
  float acc = 0.f;

  for (int base = beg; base < end; base += 64) {
    const int n = min(64, end - base);
    const int idx = (lane < n) ? __builtin_nontemporal_load(&perm[base + lane]) : 0;
    int jj = 0;
    for (; jj + 4 <= n; jj += 4) {
      const int v0 = __shfl(idx, jj + 0, 64);
      const int v1 = __shfl(idx, jj + 1, 64);
      const int v2 = __shfl(idx, jj + 2, 64);
      const int v3 = __shfl(idx, jj + 3, 64);
      const float f0 = bf2f(Xl[(size_t)v0 * 64 + lane]);
      const float f1 = bf2f(Xl[(size_t)v1 * 64 + lane]);
      const float f2 = bf2f(Xl[(size_t)v2 * 64 + lane]);
      const float f3 = bf2f(Xl[(size_t)v3 * 64 + lane]);
      acc += (f0 + f1) + (f2 + f3);
    }
    for (; jj < n; ++jj) {
      const int v = __shfl(idx, jj, 64);
      acc += bf2f(Xl[(size_t)v * 64 + lane]);
    }
  }
  const float s = degE[e] * W_edge[e];
  Xe[(size_t)e * 64 + lane] = __float2bfloat16(acc * s);
}

// ===========================================================================
// Gather 2: one wave per node. out[v] = degV[v] * sum_e Xe[e]
// ===========================================================================
__global__ __launch_bounds__(256) void gather_v_kernel(
    const bf16* __restrict__ Xe, const int* __restrict__ perm,
    const int* __restrict__ offs, const float* __restrict__ degV,
    float* __restrict__ out, int N, int E) {
  const int gtid = blockIdx.x * 256 + threadIdx.x;
  const int v    = gtid >> 6;
  const int lane = gtid & 63;
  if (v >= N) return;

  const int beg = offs[E + v];
  const int end = offs[E + v + 1];
  float acc = 0.f;

  for (int base = beg; base < end; base += 64) {
    const int n = min(64, end - base);
    const int idx = (lane < n) ? __builtin_nontemporal_load(&perm[base + lane]) : 0;
    int jj = 0;
    for (; jj + 4 <= n; jj += 4) {
      const int e0 = __shfl(idx, jj + 0, 64);
      const int e1 = __shfl(idx, jj + 1, 64);
      const int e2 = __shfl(idx, jj + 2, 64);
      const int e3 = __shfl(idx, jj + 3, 64);
      const float f0 = bf2f(Xe[(size_t)e0 * 64 + lane]);
      const float f1 = bf2f(Xe[(size_t)e1 * 64 + lane]);
      const float f2 = bf2f(Xe[(size_t)e2 * 64 + lane]);
      const float f3 = bf2f(Xe[(size_t)e3 * 64 + lane]);
      acc += (f0 + f1) + (f2 + f3);
    }
    for (; jj < n; ++jj) {
      const int e = __shfl(idx, jj, 64);
      acc += bf2f(Xe[(size_t)e * 64 + lane]);
    }
  }
  __builtin_nontemporal_store(acc * degV[v], &out[(size_t)v * 64 + lane]);
}

// ===========================================================================
extern "C" void kernel_launch(void* const* d_in, const int* in_sizes, int n_in,
                              void* d_out, int out_size, void* d_ws, size_t ws_size,
                              hipStream_t stream) {
  const float* X      = (const float*)d_in[0];
  const int*   vertex = (const int*)d_in[1];
  const int*   edges  = (const int*)d_in[2];
  const float* W      = (const float*)d_in[3];
  const float* degE   = (const float*)d_in[4];
  const float* degV   = (const float*)d_in[5];
  const float* W_edge = (const float*)d_in[6];
  float* out = (float*)d_out;

  const int nnz = in_sizes[1];
  const int E   = in_sizes[4];
  const int N   = in_sizes[5];
  const int M   = E + N;
  const int NB  = (M + 2047) / 2048;

  char* p = (char*)d_ws;
  auto alloc = [&](size_t bytes) -> void* {
    void* r = (void*)p;
    p += (bytes + 255) & ~(size_t)255;
    return r;
  };
  int*   counts = (int*)alloc((size_t)M * 4);
  int*   offs   = (int*)alloc((size_t)(M + 1) * 4);
  int*   pos    = (int*)alloc((size_t)M * 4);
  int*   bsums  = (int*)alloc(4096);
  int*   perm   = (int*)alloc((size_t)2 * nnz * 4);
  bf16*  Xl     = (bf16*)alloc((size_t)N * 64 * 2);
  bf16*  Xe     = (bf16*)alloc((size_t)E * 64 * 2);

  const int nchunks = (nnz + CHUNK - 1) / CHUNK;
  const int pgrid   = nchunks * NPART;
  const int hblocks = (nnz + 256 * 16 - 1) / (256 * 16);

  hipMemsetAsync(counts, 0, (size_t)M * 4, stream);
  hist_kernel<<<hblocks, 256, 0, stream>>>(vertex, edges, counts, nnz, E);
  scan_blocks_kernel<<<NB, 256, 0, stream>>>(counts, offs, bsums, M);
  scan_sums_kernel<<<1, 64, 0, stream>>>(bsums, offs, NB, M);
  scan_add_kernel<<<NB, 256, 0, stream>>>(offs, pos, bsums, M);
  fill_kernel<<<pgrid, 256, 0, stream>>>(vertex, edges, pos, perm, nnz, E, N);

  gemm_kernel<<<(N + 31) / 32, 256, 0, stream>>>(X, W, Xl, N);
  gather_e_kernel<<<(E + 3) / 4, 256, 0, stream>>>(Xl, perm, offs, degE, W_edge, Xe, E);
  gather_v_kernel<<<(N + 3) / 4, 256, 0, stream>>>(Xe, perm, offs, degV, out, N, E);
}

// Round 7
// 395.201 us; speedup vs baseline: 1.0009x; 1.0009x over previous
//
#include <hip/hip_runtime.h>
#include <hip/hip_bf16.h>

typedef __hip_bfloat16 bf16;
__device__ __forceinline__ float bf2f(bf16 v) { return __bfloat162float(v); }

#define BK_BITS 10
#define BK_SIZE 1024
#define MAXBK   128          // supports M = E+N up to 131072 (here 120000)
#define F1_ITEMS 4096        // incidences per bucketize block -> 8192 records

// ===========================================================================
// Histogram over unified key space [0, E+N): counts[e], counts[E+v].
// ===========================================================================
__global__ __launch_bounds__(256) void hist_kernel(
    const int* __restrict__ vertex, const int* __restrict__ edges,
    int* __restrict__ counts, int nnz, int E) {
  const int stride = gridDim.x * 256;
  for (int i = blockIdx.x * 256 + threadIdx.x; i < nnz; i += stride) {
    const int e = __builtin_nontemporal_load(&edges[i]);
    const int v = __builtin_nontemporal_load(&vertex[i]);
    atomicAdd(&counts[e], 1);
    atomicAdd(&counts[E + v], 1);
  }
}

// 2048 elements per block: thread-local 8 + Hillis-Steele over 256 threads.
__global__ __launch_bounds__(256) void scan_blocks_kernel(
    const int* __restrict__ counts, int* __restrict__ offs,
    int* __restrict__ bsums, int M) {
  __shared__ int lds[256];
  const int tid  = threadIdx.x;
  const int base = blockIdx.x * 2048 + tid * 8;
  int v[8]; int tsum = 0;
#pragma unroll
  for (int j = 0; j < 8; ++j) {
    v[j] = (base + j < M) ? counts[base + j] : 0;
    tsum += v[j];
  }
  lds[tid] = tsum;
  __syncthreads();
  for (int off = 1; off < 256; off <<= 1) {
    int t = (tid >= off) ? lds[tid - off] : 0;
    __syncthreads();
    lds[tid] += t;
    __syncthreads();
  }
  int run = lds[tid] - tsum;
#pragma unroll
  for (int j = 0; j < 8; ++j) {
    if (base + j < M) offs[base + j] = run;
    run += v[j];
  }
  if (tid == 255) bsums[blockIdx.x] = lds[255];
}

__global__ void scan_sums_kernel(int* __restrict__ bsums, int* __restrict__ offs,
                                 int NB, int M) {
  if (threadIdx.x == 0 && blockIdx.x == 0) {
    int run = 0;
    for (int b = 0; b < NB; ++b) { int t = bsums[b]; bsums[b] = run; run += t; }
    offs[M] = run;   // == 2*nnz
  }
}

__global__ __launch_bounds__(256) void scan_add_kernel(
    int* __restrict__ offs, const int* __restrict__ bsums, int M) {
  const int base = blockIdx.x * 2048 + threadIdx.x * 8;
  const int add = bsums[blockIdx.x];
#pragma unroll
  for (int j = 0; j < 8; ++j)
    if (base + j < M) offs[base + j] += add;
}

// ===========================================================================
// Init coarse-bucket cursors: gcursor[b] = offs[b << BK_BITS]
// ===========================================================================
__global__ void init_cursor_kernel(const int* __restrict__ offs,
                                   int* __restrict__ gcursor, int KB) {
  const int b = blockIdx.x * blockDim.x + threadIdx.x;
  if (b < KB) gcursor[b] = offs[b << BK_BITS];
}

// ===========================================================================
// F1: bucketize incidences into coarse buckets with DENSE writes.
// Record = (key_local:10 | val:17). Per-block LDS staging -> coalesced runs.
// ===========================================================================
__global__ __launch_bounds__(256) void bucketize_kernel(
    const int* __restrict__ vertex, const int* __restrict__ edges,
    int* __restrict__ gcursor, int* __restrict__ records,
    int nnz, int E, int KB) {
  __shared__ int cnt[MAXBK];
  __shared__ int scanEx[MAXBK];
  __shared__ int bases[MAXBK];
  __shared__ int staged[2 * F1_ITEMS];
  __shared__ unsigned char sbkt[2 * F1_ITEMS];

  const int tid    = threadIdx.x;
  const int base   = blockIdx.x * F1_ITEMS;
  const int iEnd   = min(nnz, base + F1_ITEMS);
  const int nitems = iEnd - base;

  for (int t = tid; t < MAXBK; t += 256) cnt[t] = 0;
  __syncthreads();

  int recs[32];
  int bks[32];
  int nmy = 0;
#pragma unroll
  for (int j = 0; j < 16; ++j) {
    const int i = base + tid + j * 256;
    if (i < iEnd) {
      const int e = __builtin_nontemporal_load(&edges[i]);
      const int v = __builtin_nontemporal_load(&vertex[i]);
      const int bkE = e >> BK_BITS;
      recs[nmy] = ((e & (BK_SIZE - 1)) << 17) | v;  bks[nmy] = bkE;  ++nmy;
      const int keyV = E + v;
      const int bkV = keyV >> BK_BITS;
      recs[nmy] = ((keyV & (BK_SIZE - 1)) << 17) | e;  bks[nmy] = bkV;  ++nmy;
      atomicAdd(&cnt[bkE], 1);
      atomicAdd(&cnt[bkV], 1);
    }
  }
  __syncthreads();

  // Inclusive Hillis-Steele scan of cnt into scanEx (all threads hit barriers)
  if (tid < MAXBK) scanEx[tid] = cnt[tid];
  __syncthreads();
  for (int off = 1; off < MAXBK; off <<= 1) {
    int val = 0;
    if (tid < MAXBK && tid >= off) val = scanEx[tid - off];
    __syncthreads();
    if (tid < MAXBK && tid >= off) scanEx[tid] += val;
    __syncthreads();
  }
  // Reserve global runs and convert scan to exclusive
  if (tid < MAXBK) {
    if (tid < KB && cnt[tid] > 0) bases[tid] = atomicAdd(&gcursor[tid], cnt[tid]);
    scanEx[tid] -= cnt[tid];   // now exclusive prefix
  }
  __syncthreads();
  if (tid < MAXBK) cnt[tid] = 0;
  __syncthreads();

  // Stage records grouped by bucket
  for (int r = 0; r < nmy; ++r) {
    const int b = bks[r];
    const int p = atomicAdd(&cnt[b], 1);
    const int s = scanEx[b] + p;
    staged[s] = recs[r];
    sbkt[s] = (unsigned char)b;
  }
  __syncthreads();

  // Coalesced copy-out: consecutive s within a bucket -> consecutive global
  const int nrec = 2 * nitems;
  for (int s = tid; s < nrec; s += 256) {
    const int b = sbkt[s];
    records[bases[b] + (s - scanEx[b])] = staged[s];
  }
}

// ===========================================================================
// F2: fine fill. One block per bucket; 1024 LDS cursors; perm window is
// single-XCD -> full L2 write merging. Dense record reads.
// ===========================================================================
__global__ __launch_bounds__(256) void fine_fill_kernel(
    const int* __restrict__ records, const int* __restrict__ offs,
    int* __restrict__ perm, int M) {
  __shared__ int cursors[BK_SIZE];
  const int b      = blockIdx.x;
  const int seg_lo = b << BK_BITS;
  const int seg_hi = min(M, seg_lo + BK_SIZE);
  for (int k = threadIdx.x; k < seg_hi - seg_lo; k += 256)
    cursors[k] = offs[seg_lo + k];
  __syncthreads();
  const int rbeg = offs[seg_lo];
  const int rend = offs[seg_hi];
  for (int r = rbeg + threadIdx.x; r < rend; r += 256) {
    const int rec = records[r];
    const int kl  = rec >> 17;
    const int val = rec & 0x1FFFF;
    const int p = atomicAdd(&cursors[kl], 1);
    perm[p] = val;
  }
}

// ===========================================================================
// GEMM: Xl[N,64] (bf16) = X[N,128] (f32) @ W[128,64] (f32). 32 rows/block.
// ===========================================================================
__global__ __launch_bounds__(256) void gemm_kernel(
    const float* __restrict__ X, const float* __restrict__ W,
    bf16* __restrict__ Xl, int Nrows) {
  __shared__ float ldsW[128 * 64];   // 32 KB
  __shared__ float ldsX[32][128];    // 16 KB

  const int tid = threadIdx.x;
  for (int i = tid; i < 128 * 64; i += 256) ldsW[i] = W[i];

  const int row0 = blockIdx.x * 32;
  {
    const int r    = tid >> 3;           // 0..31
    const int col0 = (tid & 7) * 16;     // 0..112
    const int rr   = row0 + r;
    if (rr < Nrows) {
      const float* src = X + (size_t)rr * 128 + col0;
      float* dst = &ldsX[r][col0];
#pragma unroll
      for (int q = 0; q < 4; ++q)
        *(float4*)(dst + q * 4) = *(const float4*)(src + q * 4);
    }
  }
  __syncthreads();

  const int c  = tid & 63;
  const int r0 = tid >> 6;       // 0..3; rows r0 + 4*j
  float acc[8];
#pragma unroll
  for (int j = 0; j < 8; ++j) acc[j] = 0.f;

  const float* __restrict__ wc = ldsW + c;
#pragma unroll 4
  for (int k = 0; k < 128; ++k) {
    const float w = wc[k * 64];
#pragma unroll
    for (int j = 0; j < 8; ++j)
      acc[j] += ldsX[r0 + j * 4][k] * w;
  }

#pragma unroll
  for (int j = 0; j < 8; ++j) {
    const int rr = row0 + r0 + j * 4;
    if (rr < Nrows) Xl[(size_t)rr * 64 + c] = __float2bfloat16(acc[j]);
  }
}

// ===========================================================================
// Gather 1: one wave per hyperedge. Xe[e] = degE[e]*W_edge[e] * sum_v Xl[v]
// ===========================================================================
__global__ __launch_bounds__(256) void gather_e_kernel(
    const bf16* __restrict__ Xl, const int* __restrict__ perm,
    const int* __restrict__ offs, const float* __restrict__ degE,
    const float* __restrict__ W_edge, bf16* __restrict__ Xe, int E) {
  const int gtid = blockIdx.x * 256 + threadIdx.x;
  const int e    = gtid >> 6;
  const int lane = gtid & 63;
  if (e >= E) return;

  const int beg = offs[e];
  const int end = offs[e + 1];
  float acc = 0.f;

  for (int base = beg; base < end; base += 64) {
    const int n = min(64, end - base);
    const int idx = (lane < n) ? perm[base + lane] : 0;
    int jj = 0;
    for (; jj + 4 <= n; jj += 4) {
      const int v0 = __shfl(idx, jj + 0, 64);
      const int v1 = __shfl(idx, jj + 1, 64);
      const int v2 = __shfl(idx, jj + 2, 64);
      const int v3 = __shfl(idx, jj + 3, 64);
      const float f0 = bf2f(Xl[(size_t)v0 * 64 + lane]);
      const float f1 = bf2f(Xl[(size_t)v1 * 64 + lane]);
      const float f2 = bf2f(Xl[(size_t)v2 * 64 + lane]);
      const float f3 = bf2f(Xl[(size_t)v3 * 64 + lane]);
      acc += (f0 + f1) + (f2 + f3);
    }
    for (; jj < n; ++jj) {
      const int v = __shfl(idx, jj, 64);
      acc += bf2f(Xl[(size_t)v * 64 + lane]);
    }
  }
  const float s = degE[e] * W_edge[e];
  Xe[(size_t)e * 64 + lane] = __float2bfloat16(acc * s);
}

// ===========================================================================
// Gather 2: one wave per node. out[v] = degV[v] * sum_e Xe[e]
// ===========================================================================
__global__ __launch_bounds__(256) void gather_v_kernel(
    const bf16* __restrict__ Xe, const int* __restrict__ perm,
    const int* __restrict__ offs, const float* __restrict__ degV,
    float* __restrict__ out, int N, int E) {
  const int gtid = blockIdx.x * 256 + threadIdx.x;
  const int v    = gtid >> 6;
  const int lane = gtid & 63;
  if (v >= N) return;

  const int beg = offs[E + v];
  const int end = offs[E + v + 1];
  float acc = 0.f;

  for (int base = beg; base < end; base += 64) {
    const int n = min(64, end - base);
    const int idx = (lane < n) ? perm[base + lane] : 0;
    int jj = 0;
    for (; jj + 4 <= n; jj += 4) {
      const int e0 = __shfl(idx, jj + 0, 64);
      const int e1 = __shfl(idx, jj + 1, 64);
      const int e2 = __shfl(idx, jj + 2, 64);
      const int e3 = __shfl(idx, jj + 3, 64);
      const float f0 = bf2f(Xe[(size_t)e0 * 64 + lane]);
      const float f1 = bf2f(Xe[(size_t)e1 * 64 + lane]);
      const float f2 = bf2f(Xe[(size_t)e2 * 64 + lane]);
      const float f3 = bf2f(Xe[(size_t)e3 * 64 + lane]);
      acc += (f0 + f1) + (f2 + f3);
    }
    for (; jj < n; ++jj) {
      const int e = __shfl(idx, jj, 64);
      acc += bf2f(Xe[(size_t)e * 64 + lane]);
    }
  }
  __builtin_nontemporal_store(acc * degV[v], &out[(size_t)v * 64 + lane]);
}

// ===========================================================================
extern "C" void kernel_launch(void* const* d_in, const int* in_sizes, int n_in,
                              void* d_out, int out_size, void* d_ws, size_t ws_size,
                              hipStream_t stream) {
  const float* X      = (const float*)d_in[0];
  const int*   vertex = (const int*)d_in[1];
  const int*   edges  = (const int*)d_in[2];
  const float* W      = (const float*)d_in[3];
  const float* degE   = (const float*)d_in[4];
  const float* degV   = (const float*)d_in[5];
  const float* W_edge = (const float*)d_in[6];
  float* out = (float*)d_out;

  const int nnz = in_sizes[1];
  const int E   = in_sizes[4];
  const int N   = in_sizes[5];
  const int M   = E + N;
  const int NB  = (M + 2047) / 2048;
  const int KB  = (M + BK_SIZE - 1) >> BK_BITS;   // coarse buckets (<=MAXBK)

  // Workspace (~24.3 MB; proven ws >= 25.3 MB from round 4-6 runs):
  // counts | offs | bsums | gcursor | perm | Xe | [records aliased with Xl]
  char* p = (char*)d_ws;
  auto alloc = [&](size_t bytes) -> void* {
    void* r = (void*)p;
    p += (bytes + 255) & ~(size_t)255;
    return r;
  };
  int*  counts  = (int*)alloc((size_t)M * 4);
  int*  offs    = (int*)alloc((size_t)(M + 1) * 4);
  int*  bsums   = (int*)alloc(4096);
  int*  gcursor = (int*)alloc(MAXBK * 4);
  int*  perm    = (int*)alloc((size_t)2 * nnz * 4);
  bf16* Xe      = (bf16*)alloc((size_t)E * 64 * 2);
  // records (2*nnz*4 = 8 MB) aliases Xl (N*64*2 = 12.8 MB): records are dead
  // after fine_fill, before gemm writes Xl.
  void* shared_region = alloc((size_t)2 * nnz * 4 > (size_t)N * 64 * 2
                                  ? (size_t)2 * nnz * 4 : (size_t)N * 64 * 2);
  int*  records = (int*)shared_region;
  bf16* Xl      = (bf16*)shared_region;

  const int hblocks = (nnz + 256 * 16 - 1) / (256 * 16);
  const int f1blocks = (nnz + F1_ITEMS - 1) / F1_ITEMS;

  hipMemsetAsync(counts, 0, (size_t)M * 4, stream);
  hist_kernel<<<hblocks, 256, 0, stream>>>(vertex, edges, counts, nnz, E);
  scan_blocks_kernel<<<NB, 256, 0, stream>>>(counts, offs, bsums, M);
  scan_sums_kernel<<<1, 64, 0, stream>>>(bsums, offs, NB, M);
  scan_add_kernel<<<NB, 256, 0, stream>>>(offs, bsums, M);

  init_cursor_kernel<<<1, MAXBK, 0, stream>>>(offs, gcursor, KB);
  bucketize_kernel<<<f1blocks, 256, 0, stream>>>(vertex, edges, gcursor, records, nnz, E, KB);
  fine_fill_kernel<<<KB, 256, 0, stream>>>(records, offs, perm, M);

  gemm_kernel<<<(N + 31) / 32, 256, 0, stream>>>(X, W, Xl, N);
  gather_e_kernel<<<(E + 3) / 4, 256, 0, stream>>>(Xl, perm, offs, degE, W_edge, Xe, E);
  gather_v_kernel<<<(N + 3) / 4, 256, 0, stream>>>(Xe, perm, offs, degV, out, N, E);
}

// Round 8
// 255.728 us; speedup vs baseline: 1.5468x; 1.5454x over previous
//
#include <hip/hip_runtime.h>
#include <hip/hip_bf16.h>

typedef __hip_bfloat16 bf16;
__device__ __forceinline__ float bf2f(bf16 v) { return __bfloat162float(v); }

#define EB_BITS 8            // 256 edge segments per bucket  (~12.8k recs)
#define VB_BITS 10           // 1024 vertex segments per bucket (~10.2k recs)
#define MAXBK   256          // bucket count ceiling (here 79+98=177)
#define F1_ITEMS 4096        // incidences per bucketize block -> 8192 records

__device__ __forceinline__ int rbase(int b, int nEB, int capE, int capV) {
  return (b < nEB) ? b * capE : nEB * capE + (b - nEB) * capV;
}

// ===========================================================================
// Init per-bucket write cursors to region bases.
// ===========================================================================
__global__ void init_cursor_kernel(int* __restrict__ gcursor, int KB,
                                   int nEB, int capE, int capV) {
  const int b = threadIdx.x;
  if (b < KB) gcursor[b] = rbase(b, nEB, capE, capV);
}

// ===========================================================================
// F1: bucketize incidences into per-bucket regions with DENSE writes.
// Record = (key_local:10 | val:17). LDS staging -> coalesced runs.
// ===========================================================================
__global__ __launch_bounds__(256) void bucketize_kernel(
    const int* __restrict__ vertex, const int* __restrict__ edges,
    int* __restrict__ gcursor, int* __restrict__ records,
    int nnz, int E, int KB, int nEB, int capE, int capV) {
  __shared__ int cnt[MAXBK];
  __shared__ int scanEx[MAXBK];
  __shared__ int bases[MAXBK];
  __shared__ int staged[2 * F1_ITEMS];
  __shared__ unsigned char sbkt[2 * F1_ITEMS];

  const int tid    = threadIdx.x;
  const int base   = blockIdx.x * F1_ITEMS;
  const int iEnd   = min(nnz, base + F1_ITEMS);
  const int nitems = iEnd - base;

  cnt[tid] = 0;
  __syncthreads();

  int recs[32];
  int bks[32];
  int nmy = 0;
#pragma unroll
  for (int j = 0; j < 16; ++j) {
    const int i = base + tid + j * 256;
    if (i < iEnd) {
      const int e = __builtin_nontemporal_load(&edges[i]);
      const int v = __builtin_nontemporal_load(&vertex[i]);
      const int bkE = e >> EB_BITS;
      recs[nmy] = ((e & ((1 << EB_BITS) - 1)) << 17) | v;  bks[nmy] = bkE;  ++nmy;
      const int bkV = nEB + (v >> VB_BITS);
      recs[nmy] = ((v & ((1 << VB_BITS) - 1)) << 17) | e;  bks[nmy] = bkV;  ++nmy;
      atomicAdd(&cnt[bkE], 1);
      atomicAdd(&cnt[bkV], 1);
    }
  }
  __syncthreads();

  // Inclusive Hillis-Steele over 256 buckets
  scanEx[tid] = cnt[tid];
  __syncthreads();
  for (int off = 1; off < MAXBK; off <<= 1) {
    int val = (tid >= off) ? scanEx[tid - off] : 0;
    __syncthreads();
    scanEx[tid] += val;
    __syncthreads();
  }
  // Reserve global runs; convert scan to exclusive
  if (tid < KB && cnt[tid] > 0) bases[tid] = atomicAdd(&gcursor[tid], cnt[tid]);
  scanEx[tid] -= cnt[tid];
  __syncthreads();
  cnt[tid] = 0;
  __syncthreads();

  // Stage records grouped by bucket
  for (int r = 0; r < nmy; ++r) {
    const int b = bks[r];
    const int p = atomicAdd(&cnt[b], 1);
    const int s = scanEx[b] + p;
    staged[s] = recs[r];
    sbkt[s] = (unsigned char)b;
  }
  __syncthreads();

  // Coalesced copy-out
  const int nrec = 2 * nitems;
  for (int s = tid; s < nrec; s += 256) {
    const int b = sbkt[s];
    records[bases[b] + (s - scanEx[b])] = staged[s];
  }
}

// ===========================================================================
// F2a: per-bucket LDS histogram + local exclusive scan.
// offs[seg] <- local exclusive offset (bucket base added later); btot[b].
// ===========================================================================
__global__ __launch_bounds__(256) void bucket_hist_kernel(
    const int* __restrict__ records, const int* __restrict__ gcursor,
    int* __restrict__ offs, int* __restrict__ btot,
    int nEB, int capE, int capV, int E, int M) {
  __shared__ int cnt[1 << VB_BITS];
  __shared__ int part[256];
  const int b   = blockIdx.x;
  const int tid = threadIdx.x;

  const int base = rbase(b, nEB, capE, capV);
  const int end  = gcursor[b];

#pragma unroll
  for (int j = 0; j < 4; ++j) cnt[tid * 4 + j] = 0;
  __syncthreads();

  for (int r = base + tid; r < end; r += 256)
    atomicAdd(&cnt[records[r] >> 17], 1);
  __syncthreads();

  // Scan 1024 counters: 4 serial per thread + 256-thread Hillis-Steele
  int c0 = cnt[tid * 4 + 0], c1 = cnt[tid * 4 + 1];
  int c2 = cnt[tid * 4 + 2], c3 = cnt[tid * 4 + 3];
  const int mysum = c0 + c1 + c2 + c3;
  part[tid] = mysum;
  __syncthreads();
  for (int off = 1; off < 256; off <<= 1) {
    int val = (tid >= off) ? part[tid - off] : 0;
    __syncthreads();
    part[tid] += val;
    __syncthreads();
  }
  int run = part[tid] - mysum;   // exclusive prefix for this thread
  cnt[tid * 4 + 0] = run;  run += c0;
  cnt[tid * 4 + 1] = run;  run += c1;
  cnt[tid * 4 + 2] = run;  run += c2;
  cnt[tid * 4 + 3] = run;
  __syncthreads();

  int seg_lo, segN;
  if (b < nEB) { seg_lo = b << EB_BITS;            segN = min(E - seg_lo, 1 << EB_BITS); }
  else         { seg_lo = E + ((b - nEB) << VB_BITS); segN = min(M - seg_lo, 1 << VB_BITS); }
  for (int k = tid; k < segN; k += 256) offs[seg_lo + k] = cnt[k];
  if (tid == 255) btot[b] = part[255];
}

// ===========================================================================
// F2b: cross-bucket exclusive scan (KB <= 256) + offs[M] sentinel.
// ===========================================================================
__global__ __launch_bounds__(256) void bucket_scan_kernel(
    const int* __restrict__ btot, int* __restrict__ bbase,
    int* __restrict__ offs, int KB, int M) {
  __shared__ int lds[256];
  const int tid = threadIdx.x;
  const int val = (tid < KB) ? btot[tid] : 0;
  lds[tid] = val;
  __syncthreads();
  for (int off = 1; off < 256; off <<= 1) {
    int t = (tid >= off) ? lds[tid - off] : 0;
    __syncthreads();
    lds[tid] += t;
    __syncthreads();
  }
  if (tid < KB) bbase[tid] = lds[tid] - val;
  if (tid == KB - 1) offs[M] = lds[tid];   // == 2*nnz
}

// ===========================================================================
// F3: per-bucket fill. Finalize offs (+bucket base) and scatter perm within
// the bucket's single-writer window (L2 write-merging).
// ===========================================================================
__global__ __launch_bounds__(256) void fill_bucket_kernel(
    const int* __restrict__ records, const int* __restrict__ gcursor,
    const int* __restrict__ bbase, int* __restrict__ offs,
    int* __restrict__ perm, int nEB, int capE, int capV, int E, int M) {
  __shared__ int cursors[1 << VB_BITS];
  const int b   = blockIdx.x;
  const int tid = threadIdx.x;

  const int base = rbase(b, nEB, capE, capV);
  const int end  = gcursor[b];
  const int bb   = bbase[b];

  int seg_lo, segN;
  if (b < nEB) { seg_lo = b << EB_BITS;               segN = min(E - seg_lo, 1 << EB_BITS); }
  else         { seg_lo = E + ((b - nEB) << VB_BITS); segN = min(M - seg_lo, 1 << VB_BITS); }

  for (int k = tid; k < segN; k += 256) {
    const int t = offs[seg_lo + k] + bb;
    cursors[k] = t;
    offs[seg_lo + k] = t;        // finalize global offs
  }
  __syncthreads();

  for (int r = base + tid; r < end; r += 256) {
    const int rec = records[r];
    const int p = atomicAdd(&cursors[rec >> 17], 1);
    perm[p] = rec & 0x1FFFF;
  }
}

// ===========================================================================
// GEMM: Xl[N,64] (bf16) = X[N,128] (f32) @ W[128,64] (f32). 32 rows/block.
// ===========================================================================
__global__ __launch_bounds__(256) void gemm_kernel(
    const float* __restrict__ X, const float* __restrict__ W,
    bf16* __restrict__ Xl, int Nrows) {
  __shared__ float ldsW[128 * 64];   // 32 KB
  __shared__ float ldsX[32][128];    // 16 KB

  const int tid = threadIdx.x;
  for (int i = tid; i < 128 * 64; i += 256) ldsW[i] = W[i];

  const int row0 = blockIdx.x * 32;
  {
    const int r    = tid >> 3;
    const int col0 = (tid & 7) * 16;
    const int rr   = row0 + r;
    if (rr < Nrows) {
      const float* src = X + (size_t)rr * 128 + col0;
      float* dst = &ldsX[r][col0];
#pragma unroll
      for (int q = 0; q < 4; ++q)
        *(float4*)(dst + q * 4) = *(const float4*)(src + q * 4);
    }
  }
  __syncthreads();

  const int c  = tid & 63;
  const int r0 = tid >> 6;
  float acc[8];
#pragma unroll
  for (int j = 0; j < 8; ++j) acc[j] = 0.f;

  const float* __restrict__ wc = ldsW + c;
#pragma unroll 4
  for (int k = 0; k < 128; ++k) {
    const float w = wc[k * 64];
#pragma unroll
    for (int j = 0; j < 8; ++j)
      acc[j] += ldsX[r0 + j * 4][k] * w;
  }

#pragma unroll
  for (int j = 0; j < 8; ++j) {
    const int rr = row0 + r0 + j * 4;
    if (rr < Nrows) Xl[(size_t)rr * 64 + c] = __float2bfloat16(acc[j]);
  }
}

// ===========================================================================
// Gather 1: one wave per hyperedge. Xe[e] = degE[e]*W_edge[e] * sum_v Xl[v]
// ===========================================================================
__global__ __launch_bounds__(256) void gather_e_kernel(
    const bf16* __restrict__ Xl, const int* __restrict__ perm,
    const int* __restrict__ offs, const float* __restrict__ degE,
    const float* __restrict__ W_edge, bf16* __restrict__ Xe, int E) {
  const int gtid = blockIdx.x * 256 + threadIdx.x;
  const int e    = gtid >> 6;
  const int lane = gtid & 63;
  if (e >= E) return;

  const int beg = offs[e];
  const int end = offs[e + 1];
  float acc = 0.f;

  for (int base = beg; base < end; base += 64) {
    const int n = min(64, end - base);
    const int idx = (lane < n) ? perm[base + lane] : 0;
    int jj = 0;
    for (; jj + 4 <= n; jj += 4) {
      const int v0 = __shfl(idx, jj + 0, 64);
      const int v1 = __shfl(idx, jj + 1, 64);
      const int v2 = __shfl(idx, jj + 2, 64);
      const int v3 = __shfl(idx, jj + 3, 64);
      const float f0 = bf2f(Xl[(size_t)v0 * 64 + lane]);
      const float f1 = bf2f(Xl[(size_t)v1 * 64 + lane]);
      const float f2 = bf2f(Xl[(size_t)v2 * 64 + lane]);
      const float f3 = bf2f(Xl[(size_t)v3 * 64 + lane]);
      acc += (f0 + f1) + (f2 + f3);
    }
    for (; jj < n; ++jj) {
      const int v = __shfl(idx, jj, 64);
      acc += bf2f(Xl[(size_t)v * 64 + lane]);
    }
  }
  const float s = degE[e] * W_edge[e];
  Xe[(size_t)e * 64 + lane] = __float2bfloat16(acc * s);
}

// ===========================================================================
// Gather 2: one wave per node. out[v] = degV[v] * sum_e Xe[e]
// ===========================================================================
__global__ __launch_bounds__(256) void gather_v_kernel(
    const bf16* __restrict__ Xe, const int* __restrict__ perm,
    const int* __restrict__ offs, const float* __restrict__ degV,
    float* __restrict__ out, int N, int E) {
  const int gtid = blockIdx.x * 256 + threadIdx.x;
  const int v    = gtid >> 6;
  const int lane = gtid & 63;
  if (v >= N) return;

  const int beg = offs[E + v];
  const int end = offs[E + v + 1];
  float acc = 0.f;

  for (int base = beg; base < end; base += 64) {
    const int n = min(64, end - base);
    const int idx = (lane < n) ? perm[base + lane] : 0;
    int jj = 0;
    for (; jj + 4 <= n; jj += 4) {
      const int e0 = __shfl(idx, jj + 0, 64);
      const int e1 = __shfl(idx, jj + 1, 64);
      const int e2 = __shfl(idx, jj + 2, 64);
      const int e3 = __shfl(idx, jj + 3, 64);
      const float f0 = bf2f(Xe[(size_t)e0 * 64 + lane]);
      const float f1 = bf2f(Xe[(size_t)e1 * 64 + lane]);
      const float f2 = bf2f(Xe[(size_t)e2 * 64 + lane]);
      const float f3 = bf2f(Xe[(size_t)e3 * 64 + lane]);
      acc += (f0 + f1) + (f2 + f3);
    }
    for (; jj < n; ++jj) {
      const int e = __shfl(idx, jj, 64);
      acc += bf2f(Xe[(size_t)e * 64 + lane]);
    }
  }
  __builtin_nontemporal_store(acc * degV[v], &out[(size_t)v * 64 + lane]);
}

// ===========================================================================
extern "C" void kernel_launch(void* const* d_in, const int* in_sizes, int n_in,
                              void* d_out, int out_size, void* d_ws, size_t ws_size,
                              hipStream_t stream) {
  const float* X      = (const float*)d_in[0];
  const int*   vertex = (const int*)d_in[1];
  const int*   edges  = (const int*)d_in[2];
  const float* W      = (const float*)d_in[3];
  const float* degE   = (const float*)d_in[4];
  const float* degV   = (const float*)d_in[5];
  const float* W_edge = (const float*)d_in[6];
  float* out = (float*)d_out;

  const int nnz = in_sizes[1];
  const int E   = in_sizes[4];
  const int N   = in_sizes[5];
  const int M   = E + N;

  const int nEB = (E + (1 << EB_BITS) - 1) >> EB_BITS;   // 79
  const int nVB = (N + (1 << VB_BITS) - 1) >> VB_BITS;   // 98
  const int KB  = nEB + nVB;                             // 177 <= MAXBK

  // Per-bucket record capacity: mean * 1.5 + 256 slack (uniform indices).
  const int capE = (nnz / nEB) * 3 / 2 + 256;
  const int capV = (nnz / nVB) * 3 / 2 + 256;
  const size_t rec_total = (size_t)nEB * capE + (size_t)nVB * capV;

  // Workspace: offs | btot | bbase | gcursor | perm | Xe | [records ~ Xl]
  char* p = (char*)d_ws;
  auto alloc = [&](size_t bytes) -> void* {
    void* r = (void*)p;
    p += (bytes + 255) & ~(size_t)255;
    return r;
  };
  int*  offs    = (int*)alloc((size_t)(M + 1) * 4);
  int*  btot    = (int*)alloc(MAXBK * 4);
  int*  bbase   = (int*)alloc(MAXBK * 4);
  int*  gcursor = (int*)alloc(MAXBK * 4);
  int*  perm    = (int*)alloc((size_t)2 * nnz * 4);
  bf16* Xe      = (bf16*)alloc((size_t)E * 64 * 2);
  // records (rec_total*4 ~ 12.1 MB) aliases Xl (N*64*2 = 12.8 MB): records
  // are dead after fill_bucket, before gemm writes Xl.
  const size_t rb = rec_total * 4, xb = (size_t)N * 64 * 2;
  void* shared_region = alloc(rb > xb ? rb : xb);
  int*  records = (int*)shared_region;
  bf16* Xl      = (bf16*)shared_region;

  const int f1blocks = (nnz + F1_ITEMS - 1) / F1_ITEMS;

  init_cursor_kernel<<<1, MAXBK, 0, stream>>>(gcursor, KB, nEB, capE, capV);
  bucketize_kernel<<<f1blocks, 256, 0, stream>>>(vertex, edges, gcursor, records,
                                                 nnz, E, KB, nEB, capE, capV);
  bucket_hist_kernel<<<KB, 256, 0, stream>>>(records, gcursor, offs, btot,
                                             nEB, capE, capV, E, M);
  bucket_scan_kernel<<<1, 256, 0, stream>>>(btot, bbase, offs, KB, M);
  fill_bucket_kernel<<<KB, 256, 0, stream>>>(records, gcursor, bbase, offs, perm,
                                             nEB, capE, capV, E, M);

  gemm_kernel<<<(N + 31) / 32, 256, 0, stream>>>(X, W, Xl, N);
  gather_e_kernel<<<(E + 3) / 4, 256, 0, stream>>>(Xl, perm, offs, degE, W_edge, Xe, E);
  gather_v_kernel<<<(N + 3) / 4, 256, 0, stream>>>(Xe, perm, offs, degV, out, N, E);
}

// Round 9
// 228.041 us; speedup vs baseline: 1.7346x; 1.1214x over previous
//
#include <hip/hip_runtime.h>
#include <hip/hip_bf16.h>

typedef __hip_bfloat16 bf16;
__device__ __forceinline__ float bf2f(bf16 v) { return __bfloat162float(v); }

typedef __attribute__((ext_vector_type(8))) short short8;
typedef __attribute__((ext_vector_type(4))) float floatx4;

#define EB_BITS 8            // 256 edge segments per bucket  (~12.8k recs)
#define VB_BITS 10           // 1024 vertex segments per bucket (~10.2k recs)
#define MAXBK   256          // bucket count ceiling (here 79+98=177)
#define F1_ITEMS 4096        // incidences per bucketize block -> 8192 records

__device__ __forceinline__ int rbase(int b, int nEB, int capE, int capV) {
  return (b < nEB) ? b * capE : nEB * capE + (b - nEB) * capV;
}

// ===========================================================================
// Init per-bucket write cursors to region bases.
// ===========================================================================
__global__ void init_cursor_kernel(int* __restrict__ gcursor, int KB,
                                   int nEB, int capE, int capV) {
  const int b = threadIdx.x;
  if (b < KB) gcursor[b] = rbase(b, nEB, capE, capV);
}

// ===========================================================================
// F1: bucketize incidences into per-bucket regions with DENSE writes.
// Record = (key_local:10 | val:17). LDS staging -> coalesced runs.
// ===========================================================================
__global__ __launch_bounds__(256) void bucketize_kernel(
    const int* __restrict__ vertex, const int* __restrict__ edges,
    int* __restrict__ gcursor, int* __restrict__ records,
    int nnz, int E, int KB, int nEB, int capE, int capV) {
  __shared__ int cnt[MAXBK];
  __shared__ int scanEx[MAXBK];
  __shared__ int bases[MAXBK];
  __shared__ int staged[2 * F1_ITEMS];
  __shared__ unsigned char sbkt[2 * F1_ITEMS];

  const int tid    = threadIdx.x;
  const int base   = blockIdx.x * F1_ITEMS;
  const int iEnd   = min(nnz, base + F1_ITEMS);
  const int nitems = iEnd - base;

  cnt[tid] = 0;
  __syncthreads();

  int recs[32];
  int bks[32];
  int nmy = 0;
#pragma unroll
  for (int j = 0; j < 16; ++j) {
    const int i = base + tid + j * 256;
    if (i < iEnd) {
      const int e = __builtin_nontemporal_load(&edges[i]);
      const int v = __builtin_nontemporal_load(&vertex[i]);
      const int bkE = e >> EB_BITS;
      recs[nmy] = ((e & ((1 << EB_BITS) - 1)) << 17) | v;  bks[nmy] = bkE;  ++nmy;
      const int bkV = nEB + (v >> VB_BITS);
      recs[nmy] = ((v & ((1 << VB_BITS) - 1)) << 17) | e;  bks[nmy] = bkV;  ++nmy;
      atomicAdd(&cnt[bkE], 1);
      atomicAdd(&cnt[bkV], 1);
    }
  }
  __syncthreads();

  // Inclusive Hillis-Steele over 256 buckets
  scanEx[tid] = cnt[tid];
  __syncthreads();
  for (int off = 1; off < MAXBK; off <<= 1) {
    int val = (tid >= off) ? scanEx[tid - off] : 0;
    __syncthreads();
    scanEx[tid] += val;
    __syncthreads();
  }
  // Reserve global runs; convert scan to exclusive
  if (tid < KB && cnt[tid] > 0) bases[tid] = atomicAdd(&gcursor[tid], cnt[tid]);
  scanEx[tid] -= cnt[tid];
  __syncthreads();
  cnt[tid] = 0;
  __syncthreads();

  // Stage records grouped by bucket
  for (int r = 0; r < nmy; ++r) {
    const int b = bks[r];
    const int p = atomicAdd(&cnt[b], 1);
    const int s = scanEx[b] + p;
    staged[s] = recs[r];
    sbkt[s] = (unsigned char)b;
  }
  __syncthreads();

  // Coalesced copy-out
  const int nrec = 2 * nitems;
  for (int s = tid; s < nrec; s += 256) {
    const int b = sbkt[s];
    records[bases[b] + (s - scanEx[b])] = staged[s];
  }
}

// ===========================================================================
// F2a: per-bucket LDS histogram + local exclusive scan.
// ===========================================================================
__global__ __launch_bounds__(256) void bucket_hist_kernel(
    const int* __restrict__ records, const int* __restrict__ gcursor,
    int* __restrict__ offs, int* __restrict__ btot,
    int nEB, int capE, int capV, int E, int M) {
  __shared__ int cnt[1 << VB_BITS];
  __shared__ int part[256];
  const int b   = blockIdx.x;
  const int tid = threadIdx.x;

  const int base = rbase(b, nEB, capE, capV);
  const int end  = gcursor[b];

#pragma unroll
  for (int j = 0; j < 4; ++j) cnt[tid * 4 + j] = 0;
  __syncthreads();

  for (int r = base + tid; r < end; r += 256)
    atomicAdd(&cnt[records[r] >> 17], 1);
  __syncthreads();

  int c0 = cnt[tid * 4 + 0], c1 = cnt[tid * 4 + 1];
  int c2 = cnt[tid * 4 + 2], c3 = cnt[tid * 4 + 3];
  const int mysum = c0 + c1 + c2 + c3;
  part[tid] = mysum;
  __syncthreads();
  for (int off = 1; off < 256; off <<= 1) {
    int val = (tid >= off) ? part[tid - off] : 0;
    __syncthreads();
    part[tid] += val;
    __syncthreads();
  }
  int run = part[tid] - mysum;
  cnt[tid * 4 + 0] = run;  run += c0;
  cnt[tid * 4 + 1] = run;  run += c1;
  cnt[tid * 4 + 2] = run;  run += c2;
  cnt[tid * 4 + 3] = run;
  __syncthreads();

  int seg_lo, segN;
  if (b < nEB) { seg_lo = b << EB_BITS;            segN = min(E - seg_lo, 1 << EB_BITS); }
  else         { seg_lo = E + ((b - nEB) << VB_BITS); segN = min(M - seg_lo, 1 << VB_BITS); }
  for (int k = tid; k < segN; k += 256) offs[seg_lo + k] = cnt[k];
  if (tid == 255) btot[b] = part[255];
}

// ===========================================================================
// F2b: cross-bucket exclusive scan (KB <= 256) + offs[M] sentinel.
// ===========================================================================
__global__ __launch_bounds__(256) void bucket_scan_kernel(
    const int* __restrict__ btot, int* __restrict__ bbase,
    int* __restrict__ offs, int KB, int M) {
  __shared__ int lds[256];
  const int tid = threadIdx.x;
  const int val = (tid < KB) ? btot[tid] : 0;
  lds[tid] = val;
  __syncthreads();
  for (int off = 1; off < 256; off <<= 1) {
    int t = (tid >= off) ? lds[tid - off] : 0;
    __syncthreads();
    lds[tid] += t;
    __syncthreads();
  }
  if (tid < KB) bbase[tid] = lds[tid] - val;
  if (tid == KB - 1) offs[M] = lds[tid];   // == 2*nnz
}

// ===========================================================================
// F3: per-bucket fill into single-writer perm window (L2 write-merging).
// ===========================================================================
__global__ __launch_bounds__(256) void fill_bucket_kernel(
    const int* __restrict__ records, const int* __restrict__ gcursor,
    const int* __restrict__ bbase, int* __restrict__ offs,
    int* __restrict__ perm, int nEB, int capE, int capV, int E, int M) {
  __shared__ int cursors[1 << VB_BITS];
  const int b   = blockIdx.x;
  const int tid = threadIdx.x;

  const int base = rbase(b, nEB, capE, capV);
  const int end  = gcursor[b];
  const int bb   = bbase[b];

  int seg_lo, segN;
  if (b < nEB) { seg_lo = b << EB_BITS;               segN = min(E - seg_lo, 1 << EB_BITS); }
  else         { seg_lo = E + ((b - nEB) << VB_BITS); segN = min(M - seg_lo, 1 << VB_BITS); }

  for (int k = tid; k < segN; k += 256) {
    const int t = offs[seg_lo + k] + bb;
    cursors[k] = t;
    offs[seg_lo + k] = t;
  }
  __syncthreads();

  for (int r = base + tid; r < end; r += 256) {
    const int rec = records[r];
    const int p = atomicAdd(&cursors[rec >> 17], 1);
    perm[p] = rec & 0x1FFFF;
  }
}

// ===========================================================================
// MFMA GEMM: Xl[N,64] (bf16) = X[N,128] (f32) @ W[128,64] (f32).
// Block = 4 waves; 64-row tile x 64 cols; K=128 via mfma_f32_16x16x32_bf16.
// W^T staged to LDS once/block, B-fragments hoisted to registers.
// A-layout: a[j] = A[m=lane&15][k=quad*8+j]; B: b[j] = B[k=quad*8+j][n=lane&15]
// C/D: col=lane&15, row=quad*4+reg  (verified layouts, learn_hip m89/m120)
// ===========================================================================
__device__ __forceinline__ unsigned int pack_bf16x2(float lo, float hi) {
  bf16 a = __float2bfloat16(lo);
  bf16 b = __float2bfloat16(hi);
  unsigned short ua = *(unsigned short*)&a;
  unsigned short ub = *(unsigned short*)&b;
  return (unsigned int)ua | ((unsigned int)ub << 16);
}

#define XS_STRIDE 136   // ushort; 16B-aligned rows, 2-way-free fragment reads

__global__ __launch_bounds__(256) void gemm_kernel(
    const float* __restrict__ X, const float* __restrict__ W,
    bf16* __restrict__ Xl, int Nrows, int ntiles) {
  __shared__ unsigned short Ws[64 * XS_STRIDE];   // W^T: [n][k] bf16, 17.4 KB
  __shared__ unsigned short Xs[64 * XS_STRIDE];   // [m][k] bf16,     17.4 KB

  const int tid  = threadIdx.x;
  const int wave = tid >> 6;
  const int lane = tid & 63;
  const int quad = lane >> 4;
  const int l15  = lane & 15;

  // Stage W^T (8192 elements, coalesced f32 reads, scalar bf16 LDS writes)
  for (int i = tid; i < 8192; i += 256) {
    const int k = i >> 6, n = i & 63;
    bf16 h = __float2bfloat16(W[i]);
    Ws[n * XS_STRIDE + k] = *(unsigned short*)&h;
  }
  __syncthreads();

  // Hoist B fragments: b[ct][kt] = W[kt*32+quad*8+j][ct*16+l15]
  short8 bfrag[4][4];
#pragma unroll
  for (int ct = 0; ct < 4; ++ct)
#pragma unroll
    for (int kt = 0; kt < 4; ++kt)
      bfrag[ct][kt] = *(const short8*)&Ws[(ct * 16 + l15) * XS_STRIDE + kt * 32 + quad * 8];

  const int r  = tid >> 2;        // staging row 0..63
  const int c0 = (tid & 3) * 32;  // staging col group

  for (int tile = blockIdx.x; tile < ntiles; tile += gridDim.x) {
    const int row0 = tile * 64;
    // Stage 64 rows of X as bf16 (32 floats/thread: 8x float4 -> 4x uint4)
    {
      int rr = row0 + r;
      if (rr >= Nrows) rr = Nrows - 1;
      const float* src = X + (size_t)rr * 128 + c0;
      unsigned short* dst = &Xs[r * XS_STRIDE + c0];
#pragma unroll
      for (int q = 0; q < 4; ++q) {
        const float4 f0 = *(const float4*)(src + q * 8);
        const float4 f1 = *(const float4*)(src + q * 8 + 4);
        uint4 o;
        o.x = pack_bf16x2(f0.x, f0.y);
        o.y = pack_bf16x2(f0.z, f0.w);
        o.z = pack_bf16x2(f1.x, f1.y);
        o.w = pack_bf16x2(f1.z, f1.w);
        *(uint4*)(dst + q * 8) = o;
      }
    }
    __syncthreads();

    // A fragments for this wave's 16 rows
    const int m = wave * 16 + l15;
    short8 afrag[4];
#pragma unroll
    for (int kt = 0; kt < 4; ++kt)
      afrag[kt] = *(const short8*)&Xs[m * XS_STRIDE + kt * 32 + quad * 8];

    floatx4 acc[4];
#pragma unroll
    for (int ct = 0; ct < 4; ++ct) {
      acc[ct] = (floatx4){0.f, 0.f, 0.f, 0.f};
#pragma unroll
      for (int kt = 0; kt < 4; ++kt)
        acc[ct] = __builtin_amdgcn_mfma_f32_16x16x32_bf16(
            afrag[kt], bfrag[ct][kt], acc[ct], 0, 0, 0);
    }

    // Store C: row = row0 + wave*16 + quad*4 + reg, col = ct*16 + l15
    const int rbase_ = row0 + wave * 16 + quad * 4;
#pragma unroll
    for (int ct = 0; ct < 4; ++ct) {
      const int col = ct * 16 + l15;
#pragma unroll
      for (int reg = 0; reg < 4; ++reg) {
        const int row = rbase_ + reg;
        if (row < Nrows) Xl[(size_t)row * 64 + col] = __float2bfloat16(acc[ct][reg]);
      }
    }
    __syncthreads();   // before next tile restages Xs
  }
}

// ===========================================================================
// Gather 1: one wave per hyperedge. Xe[e] = degE[e]*W_edge[e] * sum_v Xl[v]
// ===========================================================================
__global__ __launch_bounds__(256) void gather_e_kernel(
    const bf16* __restrict__ Xl, const int* __restrict__ perm,
    const int* __restrict__ offs, const float* __restrict__ degE,
    const float* __restrict__ W_edge, bf16* __restrict__ Xe, int E) {
  const int gtid = blockIdx.x * 256 + threadIdx.x;
  const int e    = gtid >> 6;
  const int lane = gtid & 63;
  if (e >= E) return;

  const int beg = offs[e];
  const int end = offs[e + 1];
  float acc = 0.f;

  for (int base = beg; base < end; base += 64) {
    const int n = min(64, end - base);
    const int idx = (lane < n) ? perm[base + lane] : 0;
    int jj = 0;
    for (; jj + 4 <= n; jj += 4) {
      const int v0 = __shfl(idx, jj + 0, 64);
      const int v1 = __shfl(idx, jj + 1, 64);
      const int v2 = __shfl(idx, jj + 2, 64);
      const int v3 = __shfl(idx, jj + 3, 64);
      const float f0 = bf2f(Xl[(size_t)v0 * 64 + lane]);
      const float f1 = bf2f(Xl[(size_t)v1 * 64 + lane]);
      const float f2 = bf2f(Xl[(size_t)v2 * 64 + lane]);
      const float f3 = bf2f(Xl[(size_t)v3 * 64 + lane]);
      acc += (f0 + f1) + (f2 + f3);
    }
    for (; jj < n; ++jj) {
      const int v = __shfl(idx, jj, 64);
      acc += bf2f(Xl[(size_t)v * 64 + lane]);
    }
  }
  const float s = degE[e] * W_edge[e];
  Xe[(size_t)e * 64 + lane] = __float2bfloat16(acc * s);
}

// ===========================================================================
// Gather 2: one wave per node. out[v] = degV[v] * sum_e Xe[e]
// ===========================================================================
__global__ __launch_bounds__(256) void gather_v_kernel(
    const bf16* __restrict__ Xe, const int* __restrict__ perm,
    const int* __restrict__ offs, const float* __restrict__ degV,
    float* __restrict__ out, int N, int E) {
  const int gtid = blockIdx.x * 256 + threadIdx.x;
  const int v    = gtid >> 6;
  const int lane = gtid & 63;
  if (v >= N) return;

  const int beg = offs[E + v];
  const int end = offs[E + v + 1];
  float acc = 0.f;

  for (int base = beg; base < end; base += 64) {
    const int n = min(64, end - base);
    const int idx = (lane < n) ? perm[base + lane] : 0;
    int jj = 0;
    for (; jj + 4 <= n; jj += 4) {
      const int e0 = __shfl(idx, jj + 0, 64);
      const int e1 = __shfl(idx, jj + 1, 64);
      const int e2 = __shfl(idx, jj + 2, 64);
      const int e3 = __shfl(idx, jj + 3, 64);
      const float f0 = bf2f(Xe[(size_t)e0 * 64 + lane]);
      const float f1 = bf2f(Xe[(size_t)e1 * 64 + lane]);
      const float f2 = bf2f(Xe[(size_t)e2 * 64 + lane]);
      const float f3 = bf2f(Xe[(size_t)e3 * 64 + lane]);
      acc += (f0 + f1) + (f2 + f3);
    }
    for (; jj < n; ++jj) {
      const int e = __shfl(idx, jj, 64);
      acc += bf2f(Xe[(size_t)e * 64 + lane]);
    }
  }
  __builtin_nontemporal_store(acc * degV[v], &out[(size_t)v * 64 + lane]);
}

// ===========================================================================
extern "C" void kernel_launch(void* const* d_in, const int* in_sizes, int n_in,
                              void* d_out, int out_size, void* d_ws, size_t ws_size,
                              hipStream_t stream) {
  const float* X      = (const float*)d_in[0];
  const int*   vertex = (const int*)d_in[1];
  const int*   edges  = (const int*)d_in[2];
  const float* W      = (const float*)d_in[3];
  const float* degE   = (const float*)d_in[4];
  const float* degV   = (const float*)d_in[5];
  const float* W_edge = (const float*)d_in[6];
  float* out = (float*)d_out;

  const int nnz = in_sizes[1];
  const int E   = in_sizes[4];
  const int N   = in_sizes[5];
  const int M   = E + N;

  const int nEB = (E + (1 << EB_BITS) - 1) >> EB_BITS;
  const int nVB = (N + (1 << VB_BITS) - 1) >> VB_BITS;
  const int KB  = nEB + nVB;

  const int capE = (nnz / nEB) * 3 / 2 + 256;
  const int capV = (nnz / nVB) * 3 / 2 + 256;
  const size_t rec_total = (size_t)nEB * capE + (size_t)nVB * capV;

  char* p = (char*)d_ws;
  auto alloc = [&](size_t bytes) -> void* {
    void* r = (void*)p;
    p += (bytes + 255) & ~(size_t)255;
    return r;
  };
  int*  offs    = (int*)alloc((size_t)(M + 1) * 4);
  int*  btot    = (int*)alloc(MAXBK * 4);
  int*  bbase   = (int*)alloc(MAXBK * 4);
  int*  gcursor = (int*)alloc(MAXBK * 4);
  int*  perm    = (int*)alloc((size_t)2 * nnz * 4);
  bf16* Xe      = (bf16*)alloc((size_t)E * 64 * 2);
  // records (~12.1 MB) aliases Xl (12.8 MB): records dead before gemm runs.
  const size_t rb = rec_total * 4, xb = (size_t)N * 64 * 2;
  void* shared_region = alloc(rb > xb ? rb : xb);
  int*  records = (int*)shared_region;
  bf16* Xl      = (bf16*)shared_region;

  const int f1blocks = (nnz + F1_ITEMS - 1) / F1_ITEMS;

  init_cursor_kernel<<<1, MAXBK, 0, stream>>>(gcursor, KB, nEB, capE, capV);
  bucketize_kernel<<<f1blocks, 256, 0, stream>>>(vertex, edges, gcursor, records,
                                                 nnz, E, KB, nEB, capE, capV);
  bucket_hist_kernel<<<KB, 256, 0, stream>>>(records, gcursor, offs, btot,
                                             nEB, capE, capV, E, M);
  bucket_scan_kernel<<<1, 256, 0, stream>>>(btot, bbase, offs, KB, M);
  fill_bucket_kernel<<<KB, 256, 0, stream>>>(records, gcursor, bbase, offs, perm,
                                             nEB, capE, capV, E, M);

  const int ntiles = (N + 63) / 64;
  const int gblocks = ntiles < 512 ? ntiles : 512;
  gemm_kernel<<<gblocks, 256, 0, stream>>>(X, W, Xl, N, ntiles);

  gather_e_kernel<<<(E + 3) / 4, 256, 0, stream>>>(Xl, perm, offs, degE, W_edge, Xe, E);
  gather_v_kernel<<<(N + 3) / 4, 256, 0, stream>>>(Xe, perm, offs, degV, out, N, E);
}